// Round 14
// baseline (129.208 us; speedup 1.0000x reference)
//
#include <hip/hip_runtime.h>
#include <stdint.h>

#define NSTATES 12870   // C(16,8)
#define NPAD2   18376   // padded sector-major size (axis2 and axis3 padded odd)
#define NGATES  240
#define PERIOD  15
#define NLP     16
#define TPB     1024

// ---------------- workspace layout (bytes) ----------------
#define CS_OFF      0        // float2 cs[240] : 1920
#define P01_OFF     1920     // uint32 p01[1024] : 4096 (slot-indexed)
#define P23_OFF     6016     // uint32 p23[1024] : 4096
#define BND_OFF     10112    // m3 252*16 | m2 3*420*8 | m1 3*744*4 = 23040
#define M2_OFF      4032
#define M1_OFF      14112
#define PERM_OFF    33152    // uint16 perm[12870] : 25740
#define WS_NEED     58892
#define DYNLDS      (NPAD2 * 4)

__device__ __constant__ uint8_t FREEPOS[10] = {0,1,2,5,6,9,10,13,14,15};
__device__ __constant__ uint8_t IDPOS[16] = {0,1,2,3,4,5,6,7,8,9,10,11,12,13,14,15};
__device__ __constant__ uint8_t LRANK[16] = {0,0,1,0,2,1,2,0,3,3,4,1,5,2,3,0};
__device__ __constant__ uint8_t NBT[5]  = {1,4,6,4,1};  // C(4,w)
__device__ __constant__ uint8_t PPAD[5] = {1,5,7,5,1};  // padded axis-3 size (odd)
__device__ __constant__ uint8_t PAX2[5] = {1,5,7,5,1};  // padded axis-2 size (odd)
// 21 unit classes (wa,wb) with prefix sums
__device__ __constant__ uint8_t  CLSW0[21] = {0,4,0,4,0,4, 1,1,2,2,3,3, 1,1,1, 2,2,2, 3,3,3};
__device__ __constant__ uint8_t  CLSW1[21] = {1,1,2,2,3,3, 0,4,0,4,0,4, 1,2,3, 1,2,3, 1,2,3};
__device__ __constant__ uint16_t CLSS[22] =
  {0,8,64,92,120,176,184,192,248,276,304,360,368,396,452,522,578,648,704,774,830,858};
// wave-aligned slot segments: [S,E), class A, class B (255=none), idx offset
__device__ __constant__ uint16_t SEG_S[18] = {0,64,128,192,256,320,384,412,448,512,576,640,704,768,832,896,902,908};
__device__ __constant__ uint16_t SEG_E[18] = {64,120,192,256,312,384,412,440,504,576,632,704,760,832,888,902,908,914};
__device__ __constant__ uint8_t  SEG_CA[18] = {0,2,4,6,8,10,12,20,13,14,15,16,17,18,19,14,16,18};
__device__ __constant__ uint8_t  SEG_CB[18] = {1,3,5,7,9,11,255,255,255,255,255,255,255,255,255,255,255,255};
__device__ __constant__ uint8_t  SEG_OF[18] = {0,0,0,0,0,0,0,0,0,0,0,0,0,0,0,64,64,64};

// ---------------- prep ----------------
__global__ __launch_bounds__(256) void prep_fused(
    const float* __restrict__ angles, uint8_t* __restrict__ ws) {
  __shared__ int C[17][9];
  __shared__ int SECB[5][5][5];
  if (threadIdx.x == 0) {
    for (int n = 0; n <= 16; ++n)
      for (int k = 0; k <= 8; ++k)
        C[n][k] = (k == 0) ? 1 : ((k > n) ? 0 : C[n-1][k-1] + C[n-1][k]);
    int acc = 0;
    for (int a0 = 0; a0 < 5; ++a0)
      for (int a1 = 0; a1 < 5; ++a1)
        for (int a2 = 0; a2 < 5; ++a2) {
          SECB[a0][a1][a2] = acc;
          int a3 = 8 - a0 - a1 - a2;
          if (a3 >= 0 && a3 <= 4) acc += NBT[a0] * NBT[a1] * PAX2[a2] * PPAD[a3];
        }
  }
  __syncthreads();

  auto permof = [&](uint32_t mask) -> int {
    int g0 = mask & 15, g1 = (mask >> 4) & 15, g2 = (mask >> 8) & 15, g3 = (mask >> 12) & 15;
    int w0 = __popc(g0), w1 = __popc(g1), w2 = __popc(g2), w3 = __popc(g3);
    return SECB[w0][w1][w2] +
           ((LRANK[g0] * NBT[w1] + LRANK[g1]) * PAX2[w2] + LRANK[g2]) * PPAD[w3] + LRANK[g3];
  };
  auto unrank_mask = [&](int n, int k, int r, const uint8_t* pos) -> uint32_t {
    uint32_t m = 0; int v = 0;
    for (int i = 0; i < k; ++i) {
      for (;;) { int cnt = C[n - 1 - v][k - 1 - i]; if (r < cnt) break; r -= cnt; ++v; }
      m |= 1u << pos[v]; ++v;
    }
    return m;
  };

  int u = blockIdx.x * 256 + threadIdx.x;
  if (u < 2048) {                        // pair-phase unit metadata (slot-indexed)
    const bool is01 = (u < 1024);
    const int slot = u & 1023;
    int seg = -1;
    for (int s2 = 0; s2 < 18; ++s2)
      if (slot >= SEG_S[s2] && slot < SEG_E[s2]) { seg = s2; break; }
    if (seg >= 0) {
      int r = SEG_OF[seg] + (slot - SEG_S[seg]);
      int c = SEG_CA[seg];
      int sza = CLSS[c + 1] - CLSS[c];
      if (SEG_CB[seg] != 255 && r >= sza) { r -= sza; c = SEG_CB[seg]; }
      const int wa = CLSW0[c], wb = CLSW1[c];
      const int W = 8 - wa - wb;
      int wc, wd = 0, lc = 0, ld = 0;
      for (wc = 0; wc <= 4; ++wc) {
        wd = W - wc; if (wd < 0 || wd > 4) continue;
        int n = NBT[wc] * NBT[wd];
        if (r < n) { lc = r / NBT[wd]; ld = r % NBT[wd]; break; }
        r -= n;
      }
      if (is01) {
        // class (w0,w1)=(wa,wb), fiber (w2,l2,w3,l3)=(wc,lc,wd,ld)
        int base = SECB[wa][wb][wc] + lc * PPAD[wd] + ld;
        int strd = PAX2[wc] * PPAD[wd];
        ((uint32_t*)(ws + P01_OFF))[slot] = (uint32_t)base | ((uint32_t)strd << 16);
      } else {
        // class (w2,w3)=(wa,wb), fiber (w0,l0,w1,l1)=(wc,lc,wd,ld)
        int base = SECB[wc][wd][wa] + (lc * NBT[wd] + ld) * PAX2[wa] * PPAD[wb];
        int pstr = PPAD[wb];
        ((uint32_t*)(ws + P23_OFF))[slot] = (uint32_t)base | ((uint32_t)pstr << 16);
      }
    }
  } else if (u < 2048 + 3744) {          // boundary-orbit metadata
    int v = u - 2048;
    uint8_t* bnd = ws + BND_OFF;
    const uint32_t XL[3] = {1u << 3, 1u << 7, 1u << 11};
    const uint32_t XB[3] = {(1u<<3)|(1u<<4), (1u<<7)|(1u<<8), (1u<<11)|(1u<<12)};
    if (v < 252) {                       // m3
      uint32_t mo = unrank_mask(10, 5, v, FREEPOS);
      uint32_t rep = mo | XL[0] | XL[1] | XL[2];
      uint32_t mm[8];
      for (int beta = 0; beta < 8; ++beta) {
        uint32_t m = rep;
        if (beta & 1) m ^= XB[0];
        if (beta & 2) m ^= XB[1];
        if (beta & 4) m ^= XB[2];
        mm[beta] = permof(m);
      }
      uint32_t* o = (uint32_t*)bnd + (size_t)v * 4;
      o[0] = mm[0] | (mm[1] << 16); o[1] = mm[2] | (mm[3] << 16);
      o[2] = mm[4] | (mm[5] << 16); o[3] = mm[6] | (mm[7] << 16);
    } else if (v < 1512) {               // m2
      int q = v - 252, cls = q / 420, o2 = q % 420;
      int gA = (cls == 2) ? 1 : 0;
      int gB = (cls == 0) ? 1 : 2;
      int gC = 3 - gA - gB;
      int vv = (o2 < 210) ? 0 : 1, oo = vv ? o2 - 210 : o2;
      uint32_t mo = unrank_mask(10, 6 - 2 * vv, oo, FREEPOS);
      uint32_t rep = mo | XL[gA] | XL[gB] | (vv ? XB[gC] : 0u);
      uint32_t mm[4];
      for (int beta = 0; beta < 4; ++beta) {
        uint32_t m = rep;
        if (beta & 1) m ^= XB[gA];
        if (beta & 2) m ^= XB[gB];
        mm[beta] = permof(m);
      }
      uint32_t* o = (uint32_t*)(bnd + M2_OFF + (size_t)cls * 3360) + (size_t)o2 * 2;
      o[0] = mm[0] | (mm[1] << 16); o[1] = mm[2] | (mm[3] << 16);
    } else {                             // m1
      int q = v - 1512, cls = q / 744, o2 = q % 744;
      int ia = (cls == 0) ? 1 : 0;
      int ib = (cls == 2) ? 1 : 2;
      int v1, v2, f, oo;
      if      (o2 < 120) { v1 = 0; v2 = 0; f = 7; oo = o2; }
      else if (o2 < 372) { v1 = 0; v2 = 1; f = 5; oo = o2 - 120; }
      else if (o2 < 624) { v1 = 1; v2 = 0; f = 5; oo = o2 - 372; }
      else               { v1 = 1; v2 = 1; f = 3; oo = o2 - 624; }
      uint32_t mo = unrank_mask(10, f, oo, FREEPOS);
      uint32_t rep = mo | XL[cls] | (v1 ? XB[ia] : 0u) | (v2 ? XB[ib] : 0u);
      uint32_t m0 = permof(rep), m1 = permof(rep ^ XB[cls]);
      *((uint32_t*)(bnd + M1_OFF + (size_t)cls * 2976) + o2) = m0 | (m1 << 16);
    }
  } else if (u < 2048 + 3744 + NGATES) { // cos/sin
    int g = u - (2048 + 3744);
    float t = angles[g];
    ((float2*)(ws + CS_OFF))[g] = make_float2(cosf(t), sinf(t));
  } else if (u < 2048 + 3744 + NGATES + NSTATES) {  // perm table
    int r = u - (2048 + 3744 + NGATES);
    uint32_t mask = unrank_mask(16, 8, r, IDPOS);
    ((uint16_t*)(ws + PERM_OFF))[r] = (uint16_t)permof(mask);
  }
}

__device__ __forceinline__ void rot(float& rx, float& ry, const float2 cs) {
  float nx = fmaf(cs.x, rx, cs.y * ry);
  float ny = fmaf(cs.x, ry, -cs.y * rx);
  rx = nx; ry = ny;
}
__device__ __forceinline__ float lds_ld(const float* st, uint32_t boff) {
  return *(const float*)((const char*)st + boff);
}
__device__ __forceinline__ void lds_st(float* st, uint32_t boff, float v) {
  *(float*)((char*)st + boff) = v;
}

// mix a stride-S N-vector (one axis of a unit) with the 3 in-block gates
template<int W, int S>
__device__ __forceinline__ void mix_strided(float* x,
    const float2 g1, const float2 g2, const float2 g3) {
  if constexpr (W == 1) {
    rot(x[0*S], x[1*S], g1); rot(x[2*S], x[3*S], g2); rot(x[1*S], x[2*S], g3);
  } else if constexpr (W == 2) {
    rot(x[1*S], x[2*S], g1); rot(x[3*S], x[4*S], g1);
    rot(x[1*S], x[3*S], g2); rot(x[2*S], x[4*S], g2);
    rot(x[0*S], x[1*S], g3); rot(x[4*S], x[5*S], g3);
  } else if constexpr (W == 3) {
    rot(x[2*S], x[3*S], g1); rot(x[0*S], x[1*S], g2); rot(x[1*S], x[2*S], g3);
  }
}
template<int W, int N>
__device__ __forceinline__ void mix_arr(float (&y)[N],
    const float2 g1, const float2 g2, const float2 g3) {
  mix_strided<W, 1>(&y[0], g1, g2, g3);
}

// Unit = tensor product of two mixed axes.
// NA*NB<=16: single-pass in registers (ALL axis kinds handled — R13's bug was
// missing W==2 here, silently skipping (2,0)/(0,2) classes). Larger: two-pass
// (col-wise A-mix then row-wise B-mix, <=6 live floats, thread-private LDS
// round trip) — fits the 64-VGPR budget hipcc pins for 1024-thread blocks.
template<int KA, int KB>
__device__ __forceinline__ void do_unit(float* st, uint32_t base, uint32_t sA, uint32_t sB,
    const float2 a1, const float2 a2, const float2 a3,
    const float2 b1, const float2 b2, const float2 b3) {
  constexpr int NA = (KA == 0) ? 1 : ((KA == 2) ? 6 : 4);
  constexpr int NB = (KB == 0) ? 1 : ((KB == 2) ? 6 : 4);
  if constexpr (NA * NB <= 16) {
    float x[NA * NB];
#pragma unroll
    for (int ia = 0; ia < NA; ++ia)
#pragma unroll
      for (int ib = 0; ib < NB; ++ib)
        x[ia * NB + ib] = lds_ld(st, base + ia * sA + ib * sB);
    if constexpr (KA != 0) {
#pragma unroll
      for (int ib = 0; ib < NB; ++ib) mix_strided<KA, NB>(&x[ib], a1, a2, a3);
    }
    if constexpr (KB != 0) {
#pragma unroll
      for (int ia = 0; ia < NA; ++ia) mix_strided<KB, 1>(&x[ia * NB], b1, b2, b3);
    }
#pragma unroll
    for (int ia = 0; ia < NA; ++ia)
#pragma unroll
      for (int ib = 0; ib < NB; ++ib)
        lds_st(st, base + ia * sA + ib * sB, x[ia * NB + ib]);
  } else {
    // two-pass: A-mix per column, then B-mix per row (disjoint qubits -> the
    // two gate sets commute; round trip is thread-private, no barrier)
    if constexpr (KA != 0) {
#pragma unroll
      for (int ib = 0; ib < NB; ++ib) {
        float y[NA];
#pragma unroll
        for (int ia = 0; ia < NA; ++ia) y[ia] = lds_ld(st, base + ia * sA + ib * sB);
        mix_arr<KA, NA>(y, a1, a2, a3);
#pragma unroll
        for (int ia = 0; ia < NA; ++ia) lds_st(st, base + ia * sA + ib * sB, y[ia]);
      }
    }
    if constexpr (KB != 0) {
#pragma unroll
      for (int ia = 0; ia < NA; ++ia) {
        float y[NB];
#pragma unroll
        for (int ib = 0; ib < NB; ++ib) y[ib] = lds_ld(st, base + ia * sA + ib * sB);
        mix_arr<KB, NB>(y, b1, b2, b3);
#pragma unroll
        for (int ib = 0; ib < NB; ++ib) lds_st(st, base + ia * sA + ib * sB, y[ib]);
      }
    }
  }
}

template<int KA, int KB, bool LIN>
__device__ __forceinline__ void run_unit(float* st, uint32_t md,
    const float2 a1, const float2 a2, const float2 a3,
    const float2 b1, const float2 b2, const float2 b3) {
  constexpr int NB = (KB == 0) ? 1 : ((KB == 2) ? 6 : 4);
  const uint32_t base = (md & 0xffffu) << 2;
  uint32_t sA, sB;
  if constexpr (LIN) { sB = (md >> 16) << 2; sA = NB * sB; }   // pair01
  else               { sA = (md >> 16) << 2; sB = 4; }         // pair23
  do_unit<KA, KB>(st, base, sA, sB, a1, a2, a3, b1, b2, b3);
}

// wave-aligned dispatch: each 64-lane wave runs (almost always) one class
template<bool LIN>
__device__ __forceinline__ void dispatch_pair(int tid, float* st, uint32_t md,
    const float2 a1, const float2 a2, const float2 a3,
    const float2 b1, const float2 b2, const float2 b3) {
  if (tid < 384) {
    if (tid < 128) {
      if (tid < 64)            run_unit<0,1,LIN>(st, md, a1,a2,a3, b1,b2,b3);
      else if (tid < 120)      run_unit<0,2,LIN>(st, md, a1,a2,a3, b1,b2,b3);
    } else if (tid < 256) {
      if (tid < 192)           run_unit<0,3,LIN>(st, md, a1,a2,a3, b1,b2,b3);
      else                     run_unit<1,0,LIN>(st, md, a1,a2,a3, b1,b2,b3);
    } else {
      if (tid < 312)           run_unit<2,0,LIN>(st, md, a1,a2,a3, b1,b2,b3);
      else if (tid >= 320)     run_unit<3,0,LIN>(st, md, a1,a2,a3, b1,b2,b3);
    }
  } else if (tid < 896) {
    if (tid < 512) {
      if (tid < 412)           run_unit<1,1,LIN>(st, md, a1,a2,a3, b1,b2,b3);
      else if (tid < 440)      run_unit<3,3,LIN>(st, md, a1,a2,a3, b1,b2,b3);
      else if (tid >= 448 && tid < 504) run_unit<1,2,LIN>(st, md, a1,a2,a3, b1,b2,b3);
    } else if (tid < 640) {
      if (tid < 576)           run_unit<1,3,LIN>(st, md, a1,a2,a3, b1,b2,b3);
      else if (tid < 632)      run_unit<2,1,LIN>(st, md, a1,a2,a3, b1,b2,b3);
    } else if (tid < 768) {
      if (tid < 704)           run_unit<2,2,LIN>(st, md, a1,a2,a3, b1,b2,b3);
      else if (tid < 760)      run_unit<2,3,LIN>(st, md, a1,a2,a3, b1,b2,b3);
    } else {
      if (tid < 832)           run_unit<3,1,LIN>(st, md, a1,a2,a3, b1,b2,b3);
      else if (tid < 888)      run_unit<3,2,LIN>(st, md, a1,a2,a3, b1,b2,b3);
    }
  } else if (tid < 914) {
    if (tid < 902)             run_unit<1,3,LIN>(st, md, a1,a2,a3, b1,b2,b3);
    else if (tid < 908)        run_unit<2,2,LIN>(st, md, a1,a2,a3, b1,b2,b3);
    else                       run_unit<3,1,LIN>(st, md, a1,a2,a3, b1,b2,b3);
  }
}

// ---------------- main kernel ----------------
__global__ __launch_bounds__(TPB) void rbs_fused2(
    const float* __restrict__ in, const uint8_t* __restrict__ ws,
    float* __restrict__ out) {
  extern __shared__ float st[];          // NPAD2 floats (73.5 KB dynamic)
  __shared__ float2 csl[NGATES];
  const int tid = threadIdx.x;
  const size_t row = blockIdx.x;
  const uint16_t* __restrict__ perm16 = (const uint16_t*)(ws + PERM_OFF);

  { const float* src = in + row * NSTATES;
    for (int i = tid; i < NSTATES; i += TPB) st[perm16[i]] = src[i]; }
  if (tid < NGATES) csl[tid] = ((const float2*)(ws + CS_OFF))[tid];

  // LP-invariant metadata in registers (slot-indexed; 2 regs only)
  const uint32_t md01 = ((const uint32_t*)(ws + P01_OFF))[tid];
  const uint32_t md23 = ((const uint32_t*)(ws + P23_OFF))[tid];
  const uint8_t* bnd = ws + BND_OFF;
  __syncthreads();

#pragma unroll 1
  for (int t = 0; t < NLP; ++t) {
    const int g0 = t * PERIOD;
    // pair (blocks 0,1): gates g0,g0+1,g0+8 | g0+2,g0+3,g0+10
    dispatch_pair<true>(tid, st, md01,
        csl[g0], csl[g0+1], csl[g0+8], csl[g0+2], csl[g0+3], csl[g0+10]);
    __syncthreads();
    // pair (blocks 2,3): gates g0+4,g0+5,g0+12 | g0+6,g0+7,g0+14
    dispatch_pair<false>(tid, st, md23,
        csl[g0+4], csl[g0+5], csl[g0+12], csl[g0+6], csl[g0+7], csl[g0+14]);
    __syncthreads();
    // boundary gates (3,4),(7,8),(11,12) — metadata loaded inline (L1-hit)
    const float2 c0 = csl[g0 + 9], c1 = csl[g0 + 11], c2 = csl[g0 + 13];
#pragma unroll
    for (int k = 0; k < 4; ++k) {
      int u = tid + k * 1024;
      if (u >= 3744) break;
      if (u < 252) {
        const uint4 d = ((const uint4*)bnd)[u];
        uint32_t e0 = (d.x & 0xffffu) << 2, e1 = (d.x >> 16) << 2;
        uint32_t e2 = (d.y & 0xffffu) << 2, e3 = (d.y >> 16) << 2;
        uint32_t e4 = (d.z & 0xffffu) << 2, e5 = (d.z >> 16) << 2;
        uint32_t e6 = (d.w & 0xffffu) << 2, e7 = (d.w >> 16) << 2;
        float x0 = lds_ld(st, e0), x1 = lds_ld(st, e1), x2 = lds_ld(st, e2), x3 = lds_ld(st, e3);
        float x4 = lds_ld(st, e4), x5 = lds_ld(st, e5), x6 = lds_ld(st, e6), x7 = lds_ld(st, e7);
        rot(x0, x1, c0); rot(x2, x3, c0); rot(x4, x5, c0); rot(x6, x7, c0);
        rot(x0, x2, c1); rot(x1, x3, c1); rot(x4, x6, c1); rot(x5, x7, c1);
        rot(x0, x4, c2); rot(x1, x5, c2); rot(x2, x6, c2); rot(x3, x7, c2);
        lds_st(st, e0, x0); lds_st(st, e1, x1); lds_st(st, e2, x2); lds_st(st, e3, x3);
        lds_st(st, e4, x4); lds_st(st, e5, x5); lds_st(st, e6, x6); lds_st(st, e7, x7);
      } else if (u < 1512) {
        int q = u - 252, cls = q / 420, o = q % 420;
        const uint2 m = *(const uint2*)(bnd + M2_OFF + (size_t)cls * 3360 + (size_t)o * 8);
        float2 cA = (cls == 2) ? c1 : c0;
        float2 cB = (cls == 0) ? c1 : c2;
        uint32_t e0 = (m.x & 0xffffu) << 2, e1 = (m.x >> 16) << 2;
        uint32_t e2 = (m.y & 0xffffu) << 2, e3 = (m.y >> 16) << 2;
        float x0 = lds_ld(st, e0), x1 = lds_ld(st, e1), x2 = lds_ld(st, e2), x3 = lds_ld(st, e3);
        rot(x0, x1, cA); rot(x2, x3, cA);
        rot(x0, x2, cB); rot(x1, x3, cB);
        lds_st(st, e0, x0); lds_st(st, e1, x1); lds_st(st, e2, x2); lds_st(st, e3, x3);
      } else {
        int q = u - 1512, cls = q / 744, o = q % 744;
        const uint32_t m = *((const uint32_t*)(bnd + M1_OFF + (size_t)cls * 2976) + o);
        float2 cg = (cls == 0) ? c0 : ((cls == 1) ? c1 : c2);
        uint32_t e0 = (m & 0xffffu) << 2, e1 = (m >> 16) << 2;
        float x0 = lds_ld(st, e0), x1 = lds_ld(st, e1);
        rot(x0, x1, cg);
        lds_st(st, e0, x0); lds_st(st, e1, x1);
      }
    }
    __syncthreads();
  }

  { float* dst = out + row * NSTATES;
    for (int i = tid; i < NSTATES; i += TPB) dst[i] = st[perm16[i]]; }
}

// ---------------- fallback (no workspace): per-gate raw-pairs kernel ----------------
__global__ __launch_bounds__(TPB) void rbs_raw(
    const float* __restrict__ in, const int* __restrict__ pairs_raw,
    const float* __restrict__ angles, float* __restrict__ out) {
  __shared__ float stx[NSTATES];
  __shared__ float2 csl[NGATES];
  const int tid = threadIdx.x;
  const size_t row = blockIdx.x;
  const float* src = in + row * NSTATES;
  for (int i = tid; i < NSTATES; i += TPB) stx[i] = src[i];
  for (int i = tid; i < NGATES; i += TPB) {
    float t = angles[i];
    csl[i] = make_float2(cosf(t), sinf(t));
  }
  __syncthreads();
  for (int g = 0; g < NGATES; ++g) {
    const float c = csl[g].x, s = csl[g].y;
    for (int p = tid; p < 3432; p += TPB) {
      int2 ab = ((const int2*)pairs_raw)[(size_t)g * 3432 + p];
      float xi = stx[ab.x], xj = stx[ab.y];
      stx[ab.x] = fmaf(c, xi, s * xj);
      stx[ab.y] = fmaf(c, xj, -s * xi);
    }
    __syncthreads();
  }
  float* dst = out + row * NSTATES;
  for (int i = tid; i < NSTATES; i += TPB) dst[i] = stx[i];
}

extern "C" void kernel_launch(void* const* d_in, const int* in_sizes, int n_in,
                              void* d_out, int out_size, void* d_ws, size_t ws_size,
                              hipStream_t stream) {
  const float* in = (const float*)d_in[0];
  const float* angles = (const float*)d_in[1];
  const int* pairs = (const int*)d_in[2];
  float* out = (float*)d_out;

  if (d_ws != nullptr && ws_size >= WS_NEED) {
    uint8_t* ws = (uint8_t*)d_ws;
    (void)hipFuncSetAttribute((const void*)rbs_fused2,
                              hipFuncAttributeMaxDynamicSharedMemorySize, DYNLDS);
    const int total = 2048 + 3744 + NGATES + NSTATES;  // 18902
    prep_fused<<<(total + 255) / 256, 256, 0, stream>>>(angles, ws);
    rbs_fused2<<<256, TPB, DYNLDS, stream>>>(in, ws, out);
  } else {
    rbs_raw<<<256, TPB, 0, stream>>>(in, pairs, angles, out);
  }
}

// Round 15
// 97.322 us; speedup vs baseline: 1.3276x; 1.3276x over previous
//
#include <hip/hip_runtime.h>
#include <stdint.h>

#define NSTATES 12870   // C(16,8)
#define NPAD    15378   // padded sector-major size
#define NPAIRS  3432
#define NGATES  240
#define PERIOD  15
#define NLP     16      // layer-pairs (32 layers)
#define TPB     1024

// ---------------- workspace layout (bytes) ----------------
#define CS_OFF      0
#define BLK_OFF     1920
#define BLK_BYTES   23760
#define PU_ROWS     792
#define W2_ROWS     924
#define W2_SUB_OFF  12672
#define BND_OFF     96960
#define M2_OFF      4032      // 252*16
#define M1_OFF      14112     // 4032 + 3*420*8
#define PERM_OFF    120000    // uint16 perm[12870]
#define WS_NEED     145740

__device__ __constant__ uint8_t OUTPOS[4][12] = {
  {4,5,6,7,8,9,10,11,12,13,14,15},
  {0,1,2,3,8,9,10,11,12,13,14,15},
  {0,1,2,3,4,5,6,7,12,13,14,15},
  {0,1,2,3,4,5,6,7,8,9,10,11}
};
__device__ __constant__ uint8_t FREEPOS[10] = {0,1,2,5,6,9,10,13,14,15};
__device__ __constant__ uint8_t IDPOS[16] = {0,1,2,3,4,5,6,7,8,9,10,11,12,13,14,15};
// local rank of 4-bit pattern within its weight class (numeric ascending)
__device__ __constant__ uint8_t LRANK[16] = {0,0,1,0,2,1,2,0,3,3,4,1,5,2,3,0};
__device__ __constant__ uint8_t NBT[5]  = {1,4,6,4,1};  // C(4,w)
__device__ __constant__ uint8_t PPAD[5] = {1,5,7,5,1};  // padded innermost size

// ---------------- prep: build all metadata deterministically (table-driven) ----------------
__global__ __launch_bounds__(256) void prep_fused(
    const float* __restrict__ angles, uint8_t* __restrict__ ws) {
  __shared__ int C[17][9];
  __shared__ int SECB[5][5][5];   // sector base (w0,w1,w2)
  __shared__ int ROWB[5][5][13];  // fiber-row base (ws0,ws1,outw)
  if (threadIdx.x == 0) {
    for (int n = 0; n <= 16; ++n)
      for (int k = 0; k <= 8; ++k)
        C[n][k] = (k == 0) ? 1 : ((k > n) ? 0 : C[n-1][k-1] + C[n-1][k]);
    int acc = 0;
    for (int a0 = 0; a0 < 5; ++a0)
      for (int a1 = 0; a1 < 5; ++a1)
        for (int a2 = 0; a2 < 5; ++a2) {
          SECB[a0][a1][a2] = acc;
          int a3 = 8 - a0 - a1 - a2;
          if (a3 >= 0 && a3 <= 4) acc += NBT[a0] * NBT[a1] * NBT[a2] * PPAD[a3];
        }
  }
  for (int e = threadIdx.x; e < 325; e += 256) {
    int ow = e / 25, rem = e % 25, w0 = rem / 5, w1 = rem % 5;
    int base = 0;
    for (int c0 = 0; c0 < 5; ++c0)
      for (int c1 = 0; c1 < 5; ++c1) {
        int c2 = ow - c0 - c1;
        if (c2 < 0 || c2 > 4) continue;
        if (c0 < w0 || (c0 == w0 && c1 < w1)) base += NBT[c0] * NBT[c1] * NBT[c2];
      }
    ROWB[w0][w1][ow] = base;
  }
  __syncthreads();

  auto permof = [&](uint32_t mask) -> int {
    int g0 = mask & 15, g1 = (mask >> 4) & 15, g2 = (mask >> 8) & 15, g3 = (mask >> 12) & 15;
    int w0 = __popc(g0), w1 = __popc(g1), w2 = __popc(g2), w3 = __popc(g3);
    return SECB[w0][w1][w2] +
           ((LRANK[g0] * NBT[w1] + LRANK[g1]) * NBT[w2] + LRANK[g2]) * PPAD[w3] + LRANK[g3];
  };
  auto rowof = [&](int b, uint32_t mo) -> int {
    int wsx[3], lsx[3], ii = 0;
    for (int a = 0; a < 4; ++a) if (a != b) {
      int g = (mo >> (4 * a)) & 15;
      wsx[ii] = __popc(g); lsx[ii] = LRANK[g]; ++ii;
    }
    int outw = wsx[0] + wsx[1] + wsx[2];
    return ROWB[wsx[0]][wsx[1]][outw] +
           (lsx[0] * NBT[wsx[1]] + lsx[1]) * NBT[wsx[2]] + lsx[2];
  };
  auto unrank_mask = [&](int n, int k, int r, const uint8_t* pos) -> uint32_t {
    uint32_t m = 0; int v = 0;
    for (int i = 0; i < k; ++i) {
      for (;;) { int cnt = C[n - 1 - v][k - 1 - i]; if (r < cnt) break; r -= cnt; ++v; }
      m |= 1u << pos[v]; ++v;
    }
    return m;
  };

  int u = blockIdx.x * 256 + threadIdx.x;
  if (u < 10032) {                       // block-orbit metadata
    int b = u / 2508, r = u % 2508;
    int p0 = 4 * b;
    uint32_t bmask = 0xFu << p0;
    uint8_t* blk = ws + BLK_OFF + b * BLK_BYTES;
    if (r < PU_ROWS) {                   // w=1 orbit: member m = occ at p0+m
      uint32_t mo = unrank_mask(12, 7, r, OUTPOS[b]);
      int row = rowof(b, mo);
      uint32_t m0 = permof(mo | (1u << (p0 + 0)));
      uint32_t m1 = permof(mo | (1u << (p0 + 1)));
      uint32_t m2 = permof(mo | (1u << (p0 + 2)));
      uint32_t m3 = permof(mo | (1u << (p0 + 3)));
      uint32_t* pu = (uint32_t*)blk + (size_t)row * 4;
      pu[0] = m0 | (m1 << 16); pu[1] = m2 | (m3 << 16);
    } else if (r < PU_ROWS + W2_ROWS) {  // w=2 orbit: patterns 01,02,03,12,13,23
      int o = r - PU_ROWS;
      uint32_t mo = unrank_mask(12, 6, o, OUTPOS[b]);
      int row = rowof(b, mo);
      const uint32_t pat[6] = {0x3u, 0x5u, 0x9u, 0x6u, 0xAu, 0xCu};
      uint32_t k0 = permof(mo | (pat[0] << p0)), k1 = permof(mo | (pat[1] << p0));
      uint32_t k2 = permof(mo | (pat[2] << p0)), k3 = permof(mo | (pat[3] << p0));
      uint32_t k4 = permof(mo | (pat[4] << p0)), k5 = permof(mo | (pat[5] << p0));
      uint32_t* w2 = (uint32_t*)(blk + W2_SUB_OFF) + (size_t)row * 3;
      w2[0] = k0 | (k1 << 16); w2[1] = k2 | (k3 << 16); w2[2] = k4 | (k5 << 16);
    } else {                             // w=3 orbit: member m = hole at p0+m
      int o = r - PU_ROWS - W2_ROWS;
      uint32_t mo = unrank_mask(12, 5, o, OUTPOS[b]);
      int row = rowof(b, mo);
      uint32_t j0 = permof(mo | (bmask ^ (1u << (p0 + 0))));
      uint32_t j1 = permof(mo | (bmask ^ (1u << (p0 + 1))));
      uint32_t j2 = permof(mo | (bmask ^ (1u << (p0 + 2))));
      uint32_t j3 = permof(mo | (bmask ^ (1u << (p0 + 3))));
      uint32_t* pu = (uint32_t*)blk + (size_t)row * 4;
      pu[2] = j0 | (j1 << 16); pu[3] = j2 | (j3 << 16);
    }
  } else if (u < 13776) {                // boundary-orbit metadata
    int v = u - 10032;
    uint8_t* bnd = ws + BND_OFF;
    const uint32_t XL[3] = {1u << 3, 1u << 7, 1u << 11};
    const uint32_t XB[3] = {(1u<<3)|(1u<<4), (1u<<7)|(1u<<8), (1u<<11)|(1u<<12)};
    if (v < 252) {                       // m3: all three gates active
      uint32_t mo = unrank_mask(10, 5, v, FREEPOS);
      uint32_t rep = mo | XL[0] | XL[1] | XL[2];
      uint32_t mm[8];
      for (int beta = 0; beta < 8; ++beta) {
        uint32_t m = rep;
        if (beta & 1) m ^= XB[0];
        if (beta & 2) m ^= XB[1];
        if (beta & 4) m ^= XB[2];
        mm[beta] = permof(m);
      }
      uint32_t* o = (uint32_t*)bnd + (size_t)v * 4;
      o[0] = mm[0] | (mm[1] << 16); o[1] = mm[2] | (mm[3] << 16);
      o[2] = mm[4] | (mm[5] << 16); o[3] = mm[6] | (mm[7] << 16);
    } else if (v < 1512) {               // m2: exactly two gates active
      int q = v - 252, cls = q / 420, o2 = q % 420;
      int gA = (cls == 2) ? 1 : 0;
      int gB = (cls == 0) ? 1 : 2;
      int gC = 3 - gA - gB;
      int vv = (o2 < 210) ? 0 : 1, oo = vv ? o2 - 210 : o2;
      uint32_t mo = unrank_mask(10, 6 - 2 * vv, oo, FREEPOS);
      uint32_t rep = mo | XL[gA] | XL[gB] | (vv ? XB[gC] : 0u);
      uint32_t mm[4];
      for (int beta = 0; beta < 4; ++beta) {
        uint32_t m = rep;
        if (beta & 1) m ^= XB[gA];
        if (beta & 2) m ^= XB[gB];
        mm[beta] = permof(m);
      }
      uint32_t* o = (uint32_t*)(bnd + M2_OFF + (size_t)cls * 3360) + (size_t)o2 * 2;
      o[0] = mm[0] | (mm[1] << 16); o[1] = mm[2] | (mm[3] << 16);
    } else {                             // m1: one gate active
      int q = v - 1512, cls = q / 744, o2 = q % 744;
      int ia = (cls == 0) ? 1 : 0;
      int ib = (cls == 2) ? 1 : 2;
      int v1, v2, f, oo;
      if      (o2 < 120) { v1 = 0; v2 = 0; f = 7; oo = o2; }
      else if (o2 < 372) { v1 = 0; v2 = 1; f = 5; oo = o2 - 120; }
      else if (o2 < 624) { v1 = 1; v2 = 0; f = 5; oo = o2 - 372; }
      else               { v1 = 1; v2 = 1; f = 3; oo = o2 - 624; }
      uint32_t mo = unrank_mask(10, f, oo, FREEPOS);
      uint32_t rep = mo | XL[cls] | (v1 ? XB[ia] : 0u) | (v2 ? XB[ib] : 0u);
      uint32_t m0 = permof(rep), m1 = permof(rep ^ XB[cls]);
      *((uint32_t*)(bnd + M1_OFF + (size_t)cls * 2976) + o2) = m0 | (m1 << 16);
    }
  } else if (u < 14016) {                // cos/sin
    int g = u - 13776;
    float t = angles[g];
    ((float2*)(ws + CS_OFF))[g] = make_float2(cosf(t), sinf(t));
  } else if (u < 14016 + NSTATES) {      // state permutation table
    int r = u - 14016;
    uint32_t mask = unrank_mask(16, 8, r, IDPOS);
    ((uint16_t*)(ws + PERM_OFF))[r] = (uint16_t)permof(mask);
  }
}

__device__ __forceinline__ void rot(float& rx, float& ry, const float2 cs) {
  float nx = fmaf(cs.x, rx, cs.y * ry);
  float ny = fmaf(cs.x, ry, -cs.y * rx);
  rx = nx; ry = ny;
}
__device__ __forceinline__ float lds_ld(const float* st, uint32_t boff) {
  return *(const float*)((const char*)st + boff);
}
__device__ __forceinline__ void lds_st(float* st, uint32_t boff, float v) {
  *(float*)((char*)st + boff) = v;
}

// ---------------- main kernel: R5/R7 structure (measured 94.5 us, VGPR 48, no spill) ----------------
__global__ __launch_bounds__(TPB) void rbs_fused(
    const float* __restrict__ in, const uint8_t* __restrict__ ws,
    float* __restrict__ out) {
  __shared__ float st[NPAD];
  __shared__ float2 csl[NGATES];
  const int tid = threadIdx.x;
  const size_t row = blockIdx.x;
  const uint16_t* __restrict__ perm16 = (const uint16_t*)(ws + PERM_OFF);

  { const float* src = in + row * NSTATES;
    for (int i = tid; i < NSTATES; i += TPB) st[perm16[i]] = src[i]; }
  if (tid < NGATES) csl[tid] = ((const float2*)(ws + CS_OFF))[tid];

  const uint8_t* blkbase = ws + BLK_OFF;
  const uint8_t* bnd = ws + BND_OFF;
  const int w2id = (tid < 692) ? (tid + 232) : ((tid >= 792) ? (tid - 792) : -1);

  // ---- hoist all LP-invariant metadata (byte offsets); compiler may sink ----
  uint32_t o_i[4][4], o_j[4][4], o_k[4][6];
  if (tid < PU_ROWS) {
#pragma unroll
    for (int b = 0; b < 4; ++b) {
      uint4 mu = ((const uint4*)(blkbase + b * BLK_BYTES))[tid];
      o_i[b][0] = (mu.x & 0xffffu) << 2; o_i[b][1] = (mu.x >> 16) << 2;
      o_i[b][2] = (mu.y & 0xffffu) << 2; o_i[b][3] = (mu.y >> 16) << 2;
      o_j[b][0] = (mu.z & 0xffffu) << 2; o_j[b][1] = (mu.z >> 16) << 2;
      o_j[b][2] = (mu.w & 0xffffu) << 2; o_j[b][3] = (mu.w >> 16) << 2;
    }
  }
  if (w2id >= 0) {
#pragma unroll
    for (int b = 0; b < 4; ++b) {
      const uint32_t* p = (const uint32_t*)(blkbase + b * BLK_BYTES + W2_SUB_OFF) + (size_t)w2id * 3;
      uint32_t w0 = p[0], w1 = p[1], w2v = p[2];
      o_k[b][0] = (w0 & 0xffffu) << 2; o_k[b][1] = (w0 >> 16) << 2;
      o_k[b][2] = (w1 & 0xffffu) << 2; o_k[b][3] = (w1 >> 16) << 2;
      o_k[b][4] = (w2v & 0xffffu) << 2; o_k[b][5] = (w2v >> 16) << 2;
    }
  }
  // boundary metadata (packed), per-thread fixed u's: tid, tid+1024, tid+2048, tid+3072
  uint4 bd[4];
#pragma unroll
  for (int k = 0; k < 4; ++k) {
    int u = tid + k * 1024;
    bd[k] = make_uint4(0u, 0u, 0u, 0u);
    if (u < 252) {
      bd[k] = ((const uint4*)bnd)[u];
    } else if (u < 1512) {
      int q = u - 252, cls = q / 420, o = q % 420;
      uint2 m = *(const uint2*)(bnd + M2_OFF + (size_t)cls * 3360 + (size_t)o * 8);
      bd[k].x = m.x; bd[k].y = m.y;
    } else if (u < 3744) {
      int q = u - 1512, cls = q / 744, o = q % 744;
      bd[k].x = *((const uint32_t*)(bnd + M1_OFF + (size_t)cls * 2976) + o);
    }
  }
  __syncthreads();

#pragma unroll 1
  for (int t = 0; t < NLP; ++t) {
    const int g0 = t * PERIOD;
#pragma unroll
    for (int b = 0; b < 4; ++b) {
      const float2 a1 = csl[g0 + 2 * b];
      const float2 a2 = csl[g0 + 2 * b + 1];
      const float2 a3 = csl[g0 + 8 + 2 * b];
      if (tid < PU_ROWS) {
        float x0 = lds_ld(st, o_i[b][0]), x1 = lds_ld(st, o_i[b][1]);
        float x2 = lds_ld(st, o_i[b][2]), x3 = lds_ld(st, o_i[b][3]);
        rot(x0, x1, a1); rot(x2, x3, a2); rot(x1, x2, a3);
        lds_st(st, o_i[b][0], x0); lds_st(st, o_i[b][1], x1);
        lds_st(st, o_i[b][2], x2); lds_st(st, o_i[b][3], x3);
        float y0 = lds_ld(st, o_j[b][0]), y1 = lds_ld(st, o_j[b][1]);
        float y2 = lds_ld(st, o_j[b][2]), y3 = lds_ld(st, o_j[b][3]);
        rot(y1, y0, a1); rot(y3, y2, a2); rot(y2, y1, a3);
        lds_st(st, o_j[b][0], y0); lds_st(st, o_j[b][1], y1);
        lds_st(st, o_j[b][2], y2); lds_st(st, o_j[b][3], y3);
      }
      if (w2id >= 0) {
        float z0 = lds_ld(st, o_k[b][0]), z1 = lds_ld(st, o_k[b][1]);
        float z2 = lds_ld(st, o_k[b][2]), z3 = lds_ld(st, o_k[b][3]);
        float z4 = lds_ld(st, o_k[b][4]), z5 = lds_ld(st, o_k[b][5]);
        rot(z1, z3, a1); rot(z2, z4, a1);
        rot(z1, z2, a2); rot(z3, z4, a2);
        rot(z0, z1, a3); rot(z4, z5, a3);
        lds_st(st, o_k[b][0], z0); lds_st(st, o_k[b][1], z1);
        lds_st(st, o_k[b][2], z2); lds_st(st, o_k[b][3], z3);
        lds_st(st, o_k[b][4], z4); lds_st(st, o_k[b][5], z5);
      }
      __syncthreads();
    }
    const float2 c0 = csl[g0 + 9], c1 = csl[g0 + 11], c2 = csl[g0 + 13];
#pragma unroll
    for (int k = 0; k < 4; ++k) {
      int u = tid + k * 1024;
      if (u >= 3744) break;
      uint4 d = bd[k];
      if (u < 252) {
        uint32_t e0 = (d.x & 0xffffu) << 2, e1 = (d.x >> 16) << 2;
        uint32_t e2 = (d.y & 0xffffu) << 2, e3 = (d.y >> 16) << 2;
        uint32_t e4 = (d.z & 0xffffu) << 2, e5 = (d.z >> 16) << 2;
        uint32_t e6 = (d.w & 0xffffu) << 2, e7 = (d.w >> 16) << 2;
        float x0 = lds_ld(st, e0), x1 = lds_ld(st, e1), x2 = lds_ld(st, e2), x3 = lds_ld(st, e3);
        float x4 = lds_ld(st, e4), x5 = lds_ld(st, e5), x6 = lds_ld(st, e6), x7 = lds_ld(st, e7);
        rot(x0, x1, c0); rot(x2, x3, c0); rot(x4, x5, c0); rot(x6, x7, c0);
        rot(x0, x2, c1); rot(x1, x3, c1); rot(x4, x6, c1); rot(x5, x7, c1);
        rot(x0, x4, c2); rot(x1, x5, c2); rot(x2, x6, c2); rot(x3, x7, c2);
        lds_st(st, e0, x0); lds_st(st, e1, x1); lds_st(st, e2, x2); lds_st(st, e3, x3);
        lds_st(st, e4, x4); lds_st(st, e5, x5); lds_st(st, e6, x6); lds_st(st, e7, x7);
      } else if (u < 1512) {
        int cls = (u - 252) / 420;
        float2 cA = (cls == 2) ? c1 : c0;
        float2 cB = (cls == 0) ? c1 : c2;
        uint32_t e0 = (d.x & 0xffffu) << 2, e1 = (d.x >> 16) << 2;
        uint32_t e2 = (d.y & 0xffffu) << 2, e3 = (d.y >> 16) << 2;
        float x0 = lds_ld(st, e0), x1 = lds_ld(st, e1), x2 = lds_ld(st, e2), x3 = lds_ld(st, e3);
        rot(x0, x1, cA); rot(x2, x3, cA);
        rot(x0, x2, cB); rot(x1, x3, cB);
        lds_st(st, e0, x0); lds_st(st, e1, x1); lds_st(st, e2, x2); lds_st(st, e3, x3);
      } else {
        int cls = (u - 1512) / 744;
        float2 cg = (cls == 0) ? c0 : ((cls == 1) ? c1 : c2);
        uint32_t e0 = (d.x & 0xffffu) << 2, e1 = (d.x >> 16) << 2;
        float x0 = lds_ld(st, e0), x1 = lds_ld(st, e1);
        rot(x0, x1, cg);
        lds_st(st, e0, x0); lds_st(st, e1, x1);
      }
    }
    __syncthreads();
  }

  { float* dst = out + row * NSTATES;
    for (int i = tid; i < NSTATES; i += TPB) dst[i] = st[perm16[i]]; }
}

// ---------------- fallback (no workspace): per-gate raw-pairs kernel ----------------
__global__ __launch_bounds__(TPB) void rbs_raw(
    const float* __restrict__ in, const int* __restrict__ pairs_raw,
    const float* __restrict__ angles, float* __restrict__ out) {
  __shared__ float st[NSTATES];
  __shared__ float2 csl[NGATES];
  const int tid = threadIdx.x;
  const size_t row = blockIdx.x;
  const float* src = in + row * NSTATES;
  for (int i = tid; i < NSTATES; i += TPB) st[i] = src[i];
  for (int i = tid; i < NGATES; i += TPB) {
    float t = angles[i];
    csl[i] = make_float2(cosf(t), sinf(t));
  }
  __syncthreads();
  for (int g = 0; g < NGATES; ++g) {
    const float c = csl[g].x, s = csl[g].y;
    for (int p = tid; p < NPAIRS; p += TPB) {
      int2 ab = ((const int2*)pairs_raw)[(size_t)g * NPAIRS + p];
      float xi = st[ab.x], xj = st[ab.y];
      st[ab.x] = fmaf(c, xi, s * xj);
      st[ab.y] = fmaf(c, xj, -s * xi);
    }
    __syncthreads();
  }
  float* dst = out + row * NSTATES;
  for (int i = tid; i < NSTATES; i += TPB) dst[i] = st[i];
}

extern "C" void kernel_launch(void* const* d_in, const int* in_sizes, int n_in,
                              void* d_out, int out_size, void* d_ws, size_t ws_size,
                              hipStream_t stream) {
  const float* in = (const float*)d_in[0];
  const float* angles = (const float*)d_in[1];
  const int* pairs = (const int*)d_in[2];
  float* out = (float*)d_out;

  if (d_ws != nullptr && ws_size >= WS_NEED) {
    uint8_t* ws = (uint8_t*)d_ws;
    const int total = 14016 + NSTATES;  // 26886 prep work items
    prep_fused<<<(total + 255) / 256, 256, 0, stream>>>(angles, ws);
    rbs_fused<<<256, TPB, 0, stream>>>(in, ws, out);
  } else {
    rbs_raw<<<256, TPB, 0, stream>>>(in, pairs, angles, out);
  }
}